// Round 19
// baseline (1132.801 us; speedup 1.0000x reference)
//
#include <hip/hip_runtime.h>

#define TT 1000
#define FF 20
#define HH 256
#define OO 200
#define ZR 256           // zero-row index in padded int32 tables (257 rows x 256 cols)
#define DSTR 68          // padded lane-stride (int64) for delta buffers: bank-conflict-free

typedef unsigned int uint;
typedef unsigned long long ull;

__device__ __forceinline__ int rfl(int v) { return __builtin_amdgcn_readfirstlane(v); }
__device__ __forceinline__ ull mku(ull v) {
    uint lo = (uint)rfl((int)(uint)v), hi = (uint)rfl((int)(uint)(v >> 32));
    return ((ull)hi << 32) | lo;
}

// Dual-table signed toggle-gather batch over a 64-BIT mask (single serial chain
// per word -> one load-latency exposure in the sparse-toggle common case).
// Proven no-spill array shapes (N<=8). Sign from cur bit.
// Exact int64 accumulation: (v ^ sm) - sm negates when sm = -1.
template<int N>
__device__ __forceinline__ void gstep2(const int* __restrict__ tabA, const int* __restrict__ tabB,
                                       ull& m, ull cur, int rowbase, int cx,
                                       long long* accA, long long* accB) {
    const int* pA[N];
    const int* pB[N];
    int sm[N];
#pragma unroll
    for (int u = 0; u < N; ++u) {
        int bb = __ffsll((long long)m);
        int k  = (bb ? bb : 1) - 1;
        int row = rfl(bb ? (rowbase + k) : ZR);
        int pos = rfl(bb ? (int)((cur >> k) & 1ull) : 1);
        sm[u] = pos ? 0 : -1;
        size_t off = ((size_t)row << 8) + (size_t)cx;
        pA[u] = tabA + off;
        pB[u] = tabB + off;
        m &= (m - 1);
    }
    int4 va[N], vb[N];
#pragma unroll
    for (int u = 0; u < N; ++u) { va[u] = *(const int4*)pA[u]; vb[u] = *(const int4*)pB[u]; }
#pragma unroll
    for (int u = 0; u < N; ++u) {
        accA[0] += (long long)((va[u].x ^ sm[u]) - sm[u]);
        accA[1] += (long long)((va[u].y ^ sm[u]) - sm[u]);
        accA[2] += (long long)((va[u].z ^ sm[u]) - sm[u]);
        accA[3] += (long long)((va[u].w ^ sm[u]) - sm[u]);
        accB[0] += (long long)((vb[u].x ^ sm[u]) - sm[u]);
        accB[1] += (long long)((vb[u].y ^ sm[u]) - sm[u]);
        accB[2] += (long long)((vb[u].z ^ sm[u]) - sm[u]);
        accB[3] += (long long)((vb[u].w ^ sm[u]) - sm[u]);
    }
}

// Dual-table gather over the full 64-bit toggle mask: single adaptive chain
// (K = 8/4/2). Commit via LDS int64 atomics into the [c][lane] padded delta
// layout (2-way bank aliasing = free).
__device__ __forceinline__ void gatherPair(const int* __restrict__ tabA, const int* __restrict__ tabB,
                                           ull tog, ull cur, int rowbase, int lane,
                                           long long* dstA, long long* dstB) {
    long long accA[4] = {0, 0, 0, 0}, accB[4] = {0, 0, 0, 0};
    const int cx = lane << 2;
    ull m = tog;
    while (m) {
        int pc = rfl(__popcll(m));
        if (pc > 4)      gstep2<8>(tabA, tabB, m, cur, rowbase, cx, accA, accB);
        else if (pc > 2) gstep2<4>(tabA, tabB, m, cur, rowbase, cx, accA, accB);
        else             gstep2<2>(tabA, tabB, m, cur, rowbase, cx, accA, accB);
    }
#pragma unroll
    for (int c = 0; c < 4; ++c) {
        atomicAdd((ull*)&dstA[c * DSTR + lane], (ull)accA[c]);
        atomicAdd((ull*)&dstB[c * DSTR + lane], (ull)accB[c]);
    }
}

#define INV30 9.31322574615478515625e-10   // 2^-30, exact

// 9-wave (576-thread) SINGLE-barrier pipeline (r18 champion + one edit).
// Round-19 edit (L1 waves only): the ENTIRE wx(i+1) computation (20 uniform
// LDS reads + FMAs into scalar wxn) moves to the phase HEAD — issued right
// after the fold read, so the x-reads ride the fold's latency window instead
// of queueing behind the gather commits at the tail. Only wxv stays live
// across gatherPair (same pressure as champion; r17's spill mode avoided).
// FMA order f=0..19 preserved -> bit-identical wx.
__global__ __launch_bounds__(576, 1) void snn_main(
    const float* __restrict__ x,
    const float* __restrict__ W1, const float* __restrict__ b1,
    const float* __restrict__ beta1,
    const float* __restrict__ b2, const float* __restrict__ beta2,
    const int* __restrict__ V1q, const int* __restrict__ V2q,
    const int* __restrict__ W2Tq, const int* __restrict__ WTq,
    const float* __restrict__ alpha_out, const float* __restrict__ beta_out,
    float* __restrict__ out)
{
    __shared__ float xall[TT * FF];                    // full x sequence, 80 KB
    // delta buffers: drive d (0=V1 1=W2 2=V2 3=O) x slot p x [c][lane] (stride DSTR)
    __shared__ __align__(16) long long dAll[4 * 2 * 4 * DSTR];   // ~17 KB

#define DSL(d, p) (dAll + (((d) * 2 + (p)) * 4) * DSTR)

    const int tid  = threadIdx.x;
    const int wid  = tid >> 6;
    const int lane = tid & 63;
    const int b    = blockIdx.x;
    const float* xg = x + (size_t)b * TT * FF;

    // ---- init: delta buffers + coalesced float4 preload of x (80 KB) ----
    for (int idx = tid; idx < 4 * 2 * 4 * DSTR; idx += 576) dAll[idx] = 0;
    for (int idx = tid; idx < (TT * FF) / 4; idx += 576)
        ((float4*)xall)[idx] = ((const float4*)xg)[idx];

    // L1 state (tid 0..255): W1 row in registers, drive total in register
    float syn1 = 0.f, mem1 = 0.f, beta1r = 0.f, b1r = 0.f, wxv = 0.f;
    float w1r[FF];
    long long TV1 = 0;
    bool spk1 = false;
    ull cur1 = 0ull;
    if (tid < HH) {
        beta1r = beta1[tid]; b1r = b1[tid];
#pragma unroll
        for (int f = 0; f < FF; ++f) w1r[f] = W1[tid * FF + f];
    }

    // L2 state (tid 256..511)
    float syn2 = 0.f, mem2 = 0.f, beta2r = 0.f, b2r = 0.f;
    long long TW2 = 0, TV2 = 0;
    bool spk2 = false;
    ull cur2 = 0ull;
    if (wid >= 4 && wid < 8) { beta2r = beta2[tid - HH]; b2r = b2[tid - HH]; }

    // output state (wave 8)
    float synO[4] = {0,0,0,0}, memO[4] = {0,0,0,0}, accO[4] = {0,0,0,0};
    float aOr[4] = {0,0,0,0}, bOr[4] = {0,0,0,0};
    long long TOq[4] = {0, 0, 0, 0};
    bool  spkO[4] = {false,false,false,false};
    float Mrun = 0.f;                    // running softmax shift (wave-uniform)
    if (wid == 8) {
#pragma unroll
        for (int r = 0; r < 4; ++r) {
            int o = lane + (r << 6);
            if (o < OO) { aOr[r] = alpha_out[o]; bOr[r] = beta_out[o]; }
        }
    }
    __syncthreads();
    if (tid < HH) {   // wx for t=0 (from LDS-resident x)
        float wx = b1r;
#pragma unroll
        for (int f = 0; f < FF; ++f) wx = fmaf(xall[f], w1r[f], wx);
        wxv = wx;
    }
    __syncthreads();

    for (int i = 0; i < TT + 2; ++i) {
        const int rp = (i - 1) & 1;   // fold slot (written last interval)
        const int wp = i & 1;         // gather-commit slot
        if (wid < 4) {
            // ---- L1: fold + wx(i+1) at phase head, then update + gather ----
            if (i < TT) {
                long long* slot = DSL(0, rp);
                int idx = (tid & 3) * DSTR + (tid >> 2);
                long long dv = slot[idx];                 // fold read issued first
                // wx(i+1): 20 uniform LDS reads + FMAs into a single scalar.
                // Issued now so the reads share the fold's latency window;
                // clamped index keeps it branchless (result unused at i=TT-1).
                const bool hasNext = (i + 1) < TT;
                float wxn;
                {
                    const float* xx = xall + (size_t)(hasNext ? i + 1 : 0) * FF;
                    float wx = b1r;
#pragma unroll
                    for (int f = 0; f < FF; ++f) wx = fmaf(xx[f], w1r[f], wx);
                    wxn = wx;
                }
                slot[idx] = 0;
                TV1 += dv;
                float g1 = (float)((double)TV1 * INV30);
                syn1 = fmaf(0.95f, syn1, wxv + g1);
                mem1 = fmaf(beta1r, mem1, syn1) - (spk1 ? 1.f : 0.f);
                spk1 = mem1 > 1.0f;
                ull bal = __ballot(spk1 ? 1 : 0);
                ull tog = cur1 ^ bal;
                cur1 = bal;
                if (hasNext) wxv = wxn;                   // wxn dies before gather
                if (tog) gatherPair(W2Tq, V1q, mku(tog), mku(cur1), wid << 6, lane,
                                    DSL(1, wp), DSL(0, wp));
            }
        } else if (wid < 8) {
            // ---- L2: update(i-1) + gather; both fold reads in one window ----
            if (i >= 1 && i <= TT) {
                __builtin_amdgcn_s_setprio(1);
                int j = tid - HH;
                int idx = (j & 3) * DSTR + (j >> 2);
                long long* sA = DSL(1, rp);
                long long* sB = DSL(2, rp);
                long long dA = sA[idx];
                long long dB = sB[idx];
                sA[idx] = 0;
                sB[idx] = 0;
                TW2 += dA;
                TV2 += dB;
                float gA = (float)((double)TW2 * INV30);
                float gB = (float)((double)TV2 * INV30);
                syn2 = fmaf(0.95f, syn2, b2r + gA + gB);
                mem2 = fmaf(beta2r, mem2, syn2) - (spk2 ? 1.f : 0.f);
                spk2 = mem2 > 1.0f;
                ull bal = __ballot(spk2 ? 1 : 0);
                ull tog = cur2 ^ bal;
                cur2 = bal;
                if (tog) gatherPair(WTq, V2q, mku(tog), mku(cur2), (wid - 4) << 6, lane,
                                    DSL(3, wp), DSL(2, wp));
                __builtin_amdgcn_s_setprio(0);
            }
        } else {
            // ---- wave 8: output step F(i-2) only (no global loads in loop) ----
            if (i >= 2) {
                int tF = i - 2;
                long long* sO = DSL(3, rp);
                // batch-issue the 4 fold reads (named scalars), zero, then consume
                const int x0 = ((lane      ) & 3) * DSTR + ((lane      ) >> 2);
                const int x1 = ((lane +  64) & 3) * DSTR + ((lane +  64) >> 2);
                const int x2 = ((lane + 128) & 3) * DSTR + ((lane + 128) >> 2);
                const int x3 = ((lane + 192) & 3) * DSTR + ((lane + 192) >> 2);
                long long q0 = sO[x0];
                long long q1 = sO[x1];
                long long q2 = sO[x2];
                long long q3 = sO[x3];
                sO[x0] = 0; sO[x1] = 0; sO[x2] = 0; sO[x3] = 0;
                TOq[0] += q0; TOq[1] += q1; TOq[2] += q2; TOq[3] += q3;
#pragma unroll
                for (int r = 0; r < 4; ++r) {
                    int o = lane + (r << 6);
                    if (o < OO) {
                        float ot = (float)((double)TOq[r] * INV30);
                        synO[r] = fmaf(aOr[r], synO[r], ot);
                        memO[r] = fmaf(bOr[r], memO[r], synO[r]) - (spkO[r] ? 1.f : 0.f);
                        spkO[r] = memO[r] > 1.0f;
                    }
                }
                // running-shift softmax: ex/se use Mrun (prev step's max);
                // the new-max butterfly runs INTERLEAVED with the sum butterfly.
                float ex[4]; float se = 0.f; float nmax = -3.402823466e38f;
#pragma unroll
                for (int r = 0; r < 4; ++r) {
                    int o = lane + (r << 6);
                    if (o < OO) {
                        ex[r] = __expf(memO[r] - Mrun);
                        se += ex[r];
                        nmax = fmaxf(nmax, memO[r]);
                    } else {
                        ex[r] = 0.f;
                    }
                }
#pragma unroll
                for (int off = 32; off; off >>= 1) {
                    se   += __shfl_xor(se, off, 64);
                    nmax  = fmaxf(nmax, __shfl_xor(nmax, off, 64));
                }
                if (tF > 10) {
                    float inv = __builtin_amdgcn_rcpf(se);
#pragma unroll
                    for (int r = 0; r < 4; ++r) accO[r] += ex[r] * inv;
                }
                Mrun = nmax;
            }
        }
        __syncthreads();
    }

    if (wid == 8) {
#pragma unroll
        for (int r = 0; r < 4; ++r) {
            int o = lane + (r << 6);
            if (o < OO) out[(size_t)b * OO + o] = accO[r];
        }
    }
}

// one-shot prep: padded 257x256 int32 fixed-point (2^30) tables, zero diagonal
// (V1q/V2q), zero row 256, WTq cols >= 200 zero.
__global__ void prep_kernel(const float* __restrict__ Vrec1, const float* __restrict__ Vrec2,
                            const float* __restrict__ W2, const float* __restrict__ Wout,
                            int* __restrict__ V1q, int* __restrict__ V2q,
                            int* __restrict__ W2Tq, int* __restrict__ WTq) {
    int idx = blockIdx.x * blockDim.x + threadIdx.x;   // 257*256 entries
    if (idx >= 257 * 256) return;
    int r = idx >> 8, c = idx & 255;
    float v1 = 0.f, v2 = 0.f, w2 = 0.f, wo = 0.f;
    if (r < 256) {
        if (r != c) { v1 = Vrec1[r * HH + c]; v2 = Vrec2[r * HH + c]; }
        w2 = W2[c * HH + r];
        if (c < OO) wo = Wout[c * HH + r];
    }
    const float S = 1073741824.0f;   // 2^30
    V1q[idx]  = __float2int_rn(v1 * S);
    V2q[idx]  = __float2int_rn(v2 * S);
    W2Tq[idx] = __float2int_rn(w2 * S);
    WTq[idx]  = __float2int_rn(wo * S);
}

extern "C" void kernel_launch(void* const* d_in, const int* in_sizes, int n_in,
                              void* d_out, int out_size, void* d_ws, size_t ws_size,
                              hipStream_t stream) {
    const float* x       = (const float*)d_in[0];
    const float* W1      = (const float*)d_in[1];
    const float* b1      = (const float*)d_in[2];
    const float* Vrec1   = (const float*)d_in[3];
    const float* beta1   = (const float*)d_in[4];
    const float* W2      = (const float*)d_in[5];
    const float* b2      = (const float*)d_in[6];
    const float* Vrec2   = (const float*)d_in[7];
    const float* beta2   = (const float*)d_in[8];
    const float* Wout    = (const float*)d_in[9];
    const float* alpha_o = (const float*)d_in[10];
    const float* beta_o  = (const float*)d_in[11];

    const int TBL = 257 * 256;       // int32 per padded table
    int* V1q  = (int*)d_ws;
    int* V2q  = V1q + TBL;
    int* W2Tq = V2q + TBL;
    int* WTq  = W2Tq + TBL;          // total ~1.05 MB of ws

    prep_kernel<<<(TBL + 255) / 256, 256, 0, stream>>>(Vrec1, Vrec2, W2, Wout,
                                                       V1q, V2q, W2Tq, WTq);
    snn_main<<<128, 576, 0, stream>>>(x, W1, b1, beta1, b2, beta2,
                                      V1q, V2q, W2Tq, WTq,
                                      alpha_o, beta_o, (float*)d_out);
}

// Round 20
// 1032.996 us; speedup vs baseline: 1.0966x; 1.0966x over previous
//
#include <hip/hip_runtime.h>

#define TT 1000
#define FF 20
#define HH 256
#define OO 200
#define ZR 256           // zero-row index in padded int32 tables (257 rows x 256 cols)
#define DSTR 68          // padded lane-stride (int64) for delta buffers: bank-conflict-free

typedef unsigned int uint;
typedef unsigned long long ull;

__device__ __forceinline__ int rfl(int v) { return __builtin_amdgcn_readfirstlane(v); }
__device__ __forceinline__ ull mku(ull v) {
    uint lo = (uint)rfl((int)(uint)v), hi = (uint)rfl((int)(uint)(v >> 32));
    return ((ull)hi << 32) | lo;
}

// Dual-table signed toggle-gather batch over a 64-BIT mask (single serial chain
// per word -> one load-latency exposure in the sparse-toggle common case).
// Proven no-spill array shapes (N<=8). Sign from cur bit.
// Exact int64 accumulation: (v ^ sm) - sm negates when sm = -1.
template<int N>
__device__ __forceinline__ void gstep2(const int* __restrict__ tabA, const int* __restrict__ tabB,
                                       ull& m, ull cur, int rowbase, int cx,
                                       long long* accA, long long* accB) {
    const int* pA[N];
    const int* pB[N];
    int sm[N];
#pragma unroll
    for (int u = 0; u < N; ++u) {
        int bb = __ffsll((long long)m);
        int k  = (bb ? bb : 1) - 1;
        int row = rfl(bb ? (rowbase + k) : ZR);
        int pos = rfl(bb ? (int)((cur >> k) & 1ull) : 1);
        sm[u] = pos ? 0 : -1;
        size_t off = ((size_t)row << 8) + (size_t)cx;
        pA[u] = tabA + off;
        pB[u] = tabB + off;
        m &= (m - 1);
    }
    int4 va[N], vb[N];
#pragma unroll
    for (int u = 0; u < N; ++u) { va[u] = *(const int4*)pA[u]; vb[u] = *(const int4*)pB[u]; }
#pragma unroll
    for (int u = 0; u < N; ++u) {
        accA[0] += (long long)((va[u].x ^ sm[u]) - sm[u]);
        accA[1] += (long long)((va[u].y ^ sm[u]) - sm[u]);
        accA[2] += (long long)((va[u].z ^ sm[u]) - sm[u]);
        accA[3] += (long long)((va[u].w ^ sm[u]) - sm[u]);
        accB[0] += (long long)((vb[u].x ^ sm[u]) - sm[u]);
        accB[1] += (long long)((vb[u].y ^ sm[u]) - sm[u]);
        accB[2] += (long long)((vb[u].z ^ sm[u]) - sm[u]);
        accB[3] += (long long)((vb[u].w ^ sm[u]) - sm[u]);
    }
}

// Dual-table gather over the full 64-bit toggle mask: single adaptive chain
// (K = 8/4/2). Commit via LDS int64 atomics into the [c][lane] padded delta
// layout (2-way bank aliasing = free).
__device__ __forceinline__ void gatherPair(const int* __restrict__ tabA, const int* __restrict__ tabB,
                                           ull tog, ull cur, int rowbase, int lane,
                                           long long* dstA, long long* dstB) {
    long long accA[4] = {0, 0, 0, 0}, accB[4] = {0, 0, 0, 0};
    const int cx = lane << 2;
    ull m = tog;
    while (m) {
        int pc = rfl(__popcll(m));
        if (pc > 4)      gstep2<8>(tabA, tabB, m, cur, rowbase, cx, accA, accB);
        else if (pc > 2) gstep2<4>(tabA, tabB, m, cur, rowbase, cx, accA, accB);
        else             gstep2<2>(tabA, tabB, m, cur, rowbase, cx, accA, accB);
    }
#pragma unroll
    for (int c = 0; c < 4; ++c) {
        atomicAdd((ull*)&dstA[c * DSTR + lane], (ull)accA[c]);
        atomicAdd((ull*)&dstB[c * DSTR + lane], (ull)accB[c]);
    }
}

#define INV30 9.31322574615478515625e-10   // 2^-30, exact

// 9-wave (576-thread) SINGLE-barrier pipeline (session champion, r18).
// Rotating zeroed delta buffers (2 slots): gather(i) atomic-adds into slot i&1;
// consumers fold slot (i-1)&1 into REGISTER totals and zero it.
// Waves 0-3: L1 update(i) + ballot (regs) + dual gather (W2Tq,V1q) + wx(i+1)
//   [prio-1 through the recurrence chain].
// Waves 4-7: L2 update(i-1) + ballot + dual gather (WTq,V2q) [prio-1].
// Wave 8: output step F(i-2) — batched fold reads, native __expf,
//   reciprocal-multiply, running-shift softmax (prev-step max; shift-invariant).
// Full x sequence (80 KB) LDS-preloaded at init: zero global loads in loop.
__global__ __launch_bounds__(576, 1) void snn_main(
    const float* __restrict__ x,
    const float* __restrict__ W1, const float* __restrict__ b1,
    const float* __restrict__ beta1,
    const float* __restrict__ b2, const float* __restrict__ beta2,
    const int* __restrict__ V1q, const int* __restrict__ V2q,
    const int* __restrict__ W2Tq, const int* __restrict__ WTq,
    const float* __restrict__ alpha_out, const float* __restrict__ beta_out,
    float* __restrict__ out)
{
    __shared__ float xall[TT * FF];                    // full x sequence, 80 KB
    // delta buffers: drive d (0=V1 1=W2 2=V2 3=O) x slot p x [c][lane] (stride DSTR)
    __shared__ __align__(16) long long dAll[4 * 2 * 4 * DSTR];   // ~17 KB

#define DSL(d, p) (dAll + (((d) * 2 + (p)) * 4) * DSTR)

    const int tid  = threadIdx.x;
    const int wid  = tid >> 6;
    const int lane = tid & 63;
    const int b    = blockIdx.x;
    const float* xg = x + (size_t)b * TT * FF;

    // ---- init: delta buffers + coalesced float4 preload of x (80 KB) ----
    for (int idx = tid; idx < 4 * 2 * 4 * DSTR; idx += 576) dAll[idx] = 0;
    for (int idx = tid; idx < (TT * FF) / 4; idx += 576)
        ((float4*)xall)[idx] = ((const float4*)xg)[idx];

    // L1 state (tid 0..255): W1 row in registers, drive total in register
    float syn1 = 0.f, mem1 = 0.f, beta1r = 0.f, b1r = 0.f, wxv = 0.f;
    float w1r[FF];
    long long TV1 = 0;
    bool spk1 = false;
    ull cur1 = 0ull;
    if (tid < HH) {
        beta1r = beta1[tid]; b1r = b1[tid];
#pragma unroll
        for (int f = 0; f < FF; ++f) w1r[f] = W1[tid * FF + f];
    }

    // L2 state (tid 256..511)
    float syn2 = 0.f, mem2 = 0.f, beta2r = 0.f, b2r = 0.f;
    long long TW2 = 0, TV2 = 0;
    bool spk2 = false;
    ull cur2 = 0ull;
    if (wid >= 4 && wid < 8) { beta2r = beta2[tid - HH]; b2r = b2[tid - HH]; }

    // output state (wave 8)
    float synO[4] = {0,0,0,0}, memO[4] = {0,0,0,0}, accO[4] = {0,0,0,0};
    float aOr[4] = {0,0,0,0}, bOr[4] = {0,0,0,0};
    long long TOq[4] = {0, 0, 0, 0};
    bool  spkO[4] = {false,false,false,false};
    float Mrun = 0.f;                    // running softmax shift (wave-uniform)
    if (wid == 8) {
#pragma unroll
        for (int r = 0; r < 4; ++r) {
            int o = lane + (r << 6);
            if (o < OO) { aOr[r] = alpha_out[o]; bOr[r] = beta_out[o]; }
        }
    }
    __syncthreads();
    if (tid < HH) {   // wx for t=0 (from LDS-resident x)
        float wx = b1r;
#pragma unroll
        for (int f = 0; f < FF; ++f) wx = fmaf(xall[f], w1r[f], wx);
        wxv = wx;
    }
    __syncthreads();

    for (int i = 0; i < TT + 2; ++i) {
        const int rp = (i - 1) & 1;   // fold slot (written last interval)
        const int wp = i & 1;         // gather-commit slot
        if (wid < 4) {
            // ---- L1: update(i) + gather + wx(i+1) ----
            if (i < TT) {
                __builtin_amdgcn_s_setprio(1);
                long long* slot = DSL(0, rp);
                int idx = (tid & 3) * DSTR + (tid >> 2);
                TV1 += slot[idx]; slot[idx] = 0;
                float g1 = (float)((double)TV1 * INV30);
                syn1 = fmaf(0.95f, syn1, wxv + g1);
                mem1 = fmaf(beta1r, mem1, syn1) - (spk1 ? 1.f : 0.f);
                spk1 = mem1 > 1.0f;
                ull bal = __ballot(spk1 ? 1 : 0);
                ull tog = cur1 ^ bal;
                cur1 = bal;
                if (tog) gatherPair(W2Tq, V1q, mku(tog), mku(cur1), wid << 6, lane,
                                    DSL(1, wp), DSL(0, wp));
                __builtin_amdgcn_s_setprio(0);
                if ((i + 1) < TT) {
                    const float* xx = xall + (size_t)(i + 1) * FF;
                    float wx = b1r;
#pragma unroll
                    for (int f = 0; f < FF; ++f) wx = fmaf(xx[f], w1r[f], wx);
                    wxv = wx;
                }
            }
        } else if (wid < 8) {
            // ---- L2: update(i-1) + gather; both fold reads in one window ----
            if (i >= 1 && i <= TT) {
                __builtin_amdgcn_s_setprio(1);
                int j = tid - HH;
                int idx = (j & 3) * DSTR + (j >> 2);
                long long* sA = DSL(1, rp);
                long long* sB = DSL(2, rp);
                long long dA = sA[idx];
                long long dB = sB[idx];
                sA[idx] = 0;
                sB[idx] = 0;
                TW2 += dA;
                TV2 += dB;
                float gA = (float)((double)TW2 * INV30);
                float gB = (float)((double)TV2 * INV30);
                syn2 = fmaf(0.95f, syn2, b2r + gA + gB);
                mem2 = fmaf(beta2r, mem2, syn2) - (spk2 ? 1.f : 0.f);
                spk2 = mem2 > 1.0f;
                ull bal = __ballot(spk2 ? 1 : 0);
                ull tog = cur2 ^ bal;
                cur2 = bal;
                if (tog) gatherPair(WTq, V2q, mku(tog), mku(cur2), (wid - 4) << 6, lane,
                                    DSL(3, wp), DSL(2, wp));
                __builtin_amdgcn_s_setprio(0);
            }
        } else {
            // ---- wave 8: output step F(i-2) only (no global loads in loop) ----
            if (i >= 2) {
                int tF = i - 2;
                long long* sO = DSL(3, rp);
                // batch-issue the 4 fold reads (named scalars), zero, then consume
                const int x0 = ((lane      ) & 3) * DSTR + ((lane      ) >> 2);
                const int x1 = ((lane +  64) & 3) * DSTR + ((lane +  64) >> 2);
                const int x2 = ((lane + 128) & 3) * DSTR + ((lane + 128) >> 2);
                const int x3 = ((lane + 192) & 3) * DSTR + ((lane + 192) >> 2);
                long long q0 = sO[x0];
                long long q1 = sO[x1];
                long long q2 = sO[x2];
                long long q3 = sO[x3];
                sO[x0] = 0; sO[x1] = 0; sO[x2] = 0; sO[x3] = 0;
                TOq[0] += q0; TOq[1] += q1; TOq[2] += q2; TOq[3] += q3;
#pragma unroll
                for (int r = 0; r < 4; ++r) {
                    int o = lane + (r << 6);
                    if (o < OO) {
                        float ot = (float)((double)TOq[r] * INV30);
                        synO[r] = fmaf(aOr[r], synO[r], ot);
                        memO[r] = fmaf(bOr[r], memO[r], synO[r]) - (spkO[r] ? 1.f : 0.f);
                        spkO[r] = memO[r] > 1.0f;
                    }
                }
                // running-shift softmax: ex/se use Mrun (prev step's max);
                // the new-max butterfly runs INTERLEAVED with the sum butterfly.
                float ex[4]; float se = 0.f; float nmax = -3.402823466e38f;
#pragma unroll
                for (int r = 0; r < 4; ++r) {
                    int o = lane + (r << 6);
                    if (o < OO) {
                        ex[r] = __expf(memO[r] - Mrun);
                        se += ex[r];
                        nmax = fmaxf(nmax, memO[r]);
                    } else {
                        ex[r] = 0.f;
                    }
                }
#pragma unroll
                for (int off = 32; off; off >>= 1) {
                    se   += __shfl_xor(se, off, 64);
                    nmax  = fmaxf(nmax, __shfl_xor(nmax, off, 64));
                }
                if (tF > 10) {
                    float inv = __builtin_amdgcn_rcpf(se);
#pragma unroll
                    for (int r = 0; r < 4; ++r) accO[r] += ex[r] * inv;
                }
                Mrun = nmax;
            }
        }
        __syncthreads();
    }

    if (wid == 8) {
#pragma unroll
        for (int r = 0; r < 4; ++r) {
            int o = lane + (r << 6);
            if (o < OO) out[(size_t)b * OO + o] = accO[r];
        }
    }
}

// one-shot prep: padded 257x256 int32 fixed-point (2^30) tables, zero diagonal
// (V1q/V2q), zero row 256, WTq cols >= 200 zero.
__global__ void prep_kernel(const float* __restrict__ Vrec1, const float* __restrict__ Vrec2,
                            const float* __restrict__ W2, const float* __restrict__ Wout,
                            int* __restrict__ V1q, int* __restrict__ V2q,
                            int* __restrict__ W2Tq, int* __restrict__ WTq) {
    int idx = blockIdx.x * blockDim.x + threadIdx.x;   // 257*256 entries
    if (idx >= 257 * 256) return;
    int r = idx >> 8, c = idx & 255;
    float v1 = 0.f, v2 = 0.f, w2 = 0.f, wo = 0.f;
    if (r < 256) {
        if (r != c) { v1 = Vrec1[r * HH + c]; v2 = Vrec2[r * HH + c]; }
        w2 = W2[c * HH + r];
        if (c < OO) wo = Wout[c * HH + r];
    }
    const float S = 1073741824.0f;   // 2^30
    V1q[idx]  = __float2int_rn(v1 * S);
    V2q[idx]  = __float2int_rn(v2 * S);
    W2Tq[idx] = __float2int_rn(w2 * S);
    WTq[idx]  = __float2int_rn(wo * S);
}

extern "C" void kernel_launch(void* const* d_in, const int* in_sizes, int n_in,
                              void* d_out, int out_size, void* d_ws, size_t ws_size,
                              hipStream_t stream) {
    const float* x       = (const float*)d_in[0];
    const float* W1      = (const float*)d_in[1];
    const float* b1      = (const float*)d_in[2];
    const float* Vrec1   = (const float*)d_in[3];
    const float* beta1   = (const float*)d_in[4];
    const float* W2      = (const float*)d_in[5];
    const float* b2      = (const float*)d_in[6];
    const float* Vrec2   = (const float*)d_in[7];
    const float* beta2   = (const float*)d_in[8];
    const float* Wout    = (const float*)d_in[9];
    const float* alpha_o = (const float*)d_in[10];
    const float* beta_o  = (const float*)d_in[11];

    const int TBL = 257 * 256;       // int32 per padded table
    int* V1q  = (int*)d_ws;
    int* V2q  = V1q + TBL;
    int* W2Tq = V2q + TBL;
    int* WTq  = W2Tq + TBL;          // total ~1.05 MB of ws

    prep_kernel<<<(TBL + 255) / 256, 256, 0, stream>>>(Vrec1, Vrec2, W2, Wout,
                                                       V1q, V2q, W2Tq, WTq);
    snn_main<<<128, 576, 0, stream>>>(x, W1, b1, beta1, b2, beta2,
                                      V1q, V2q, W2Tq, WTq,
                                      alpha_o, beta_o, (float*)d_out);
}

// Round 21
// 1029.794 us; speedup vs baseline: 1.1000x; 1.0031x over previous
//
#include <hip/hip_runtime.h>

#define TT 1000
#define FF 20
#define HH 256
#define OO 200
#define ZR 256           // zero-row index in padded int32 tables (257 rows x 256 cols)
#define DSTR 68          // padded lane-stride (int64) for delta buffers: bank-conflict-free

typedef unsigned int uint;
typedef unsigned long long ull;

__device__ __forceinline__ int rfl(int v) { return __builtin_amdgcn_readfirstlane(v); }
__device__ __forceinline__ ull mku(ull v) {
    uint lo = (uint)rfl((int)(uint)v), hi = (uint)rfl((int)(uint)(v >> 32));
    return ((ull)hi << 32) | lo;
}

// Dual-table signed toggle-gather batch over a 64-BIT mask (single serial chain
// per word -> one load-latency exposure in the sparse-toggle common case).
// Proven no-spill array shapes (N<=8). Sign from cur bit.
// Exact int64 accumulation: (v ^ sm) - sm negates when sm = -1.
template<int N>
__device__ __forceinline__ void gstep2(const int* __restrict__ tabA, const int* __restrict__ tabB,
                                       ull& m, ull cur, int rowbase, int cx,
                                       long long* accA, long long* accB) {
    const int* pA[N];
    const int* pB[N];
    int sm[N];
#pragma unroll
    for (int u = 0; u < N; ++u) {
        int bb = __ffsll((long long)m);
        int k  = (bb ? bb : 1) - 1;
        int row = rfl(bb ? (rowbase + k) : ZR);
        int pos = rfl(bb ? (int)((cur >> k) & 1ull) : 1);
        sm[u] = pos ? 0 : -1;
        size_t off = ((size_t)row << 8) + (size_t)cx;
        pA[u] = tabA + off;
        pB[u] = tabB + off;
        m &= (m - 1);
    }
    int4 va[N], vb[N];
#pragma unroll
    for (int u = 0; u < N; ++u) { va[u] = *(const int4*)pA[u]; vb[u] = *(const int4*)pB[u]; }
#pragma unroll
    for (int u = 0; u < N; ++u) {
        accA[0] += (long long)((va[u].x ^ sm[u]) - sm[u]);
        accA[1] += (long long)((va[u].y ^ sm[u]) - sm[u]);
        accA[2] += (long long)((va[u].z ^ sm[u]) - sm[u]);
        accA[3] += (long long)((va[u].w ^ sm[u]) - sm[u]);
        accB[0] += (long long)((vb[u].x ^ sm[u]) - sm[u]);
        accB[1] += (long long)((vb[u].y ^ sm[u]) - sm[u]);
        accB[2] += (long long)((vb[u].z ^ sm[u]) - sm[u]);
        accB[3] += (long long)((vb[u].w ^ sm[u]) - sm[u]);
    }
}

// Dual-table gather over the full 64-bit toggle mask: single adaptive chain
// (K = 8/4/2). Commit via LDS int64 atomics into the [c][lane] padded delta
// layout (2-way bank aliasing = free).
__device__ __forceinline__ void gatherPair(const int* __restrict__ tabA, const int* __restrict__ tabB,
                                           ull tog, ull cur, int rowbase, int lane,
                                           long long* dstA, long long* dstB) {
    long long accA[4] = {0, 0, 0, 0}, accB[4] = {0, 0, 0, 0};
    const int cx = lane << 2;
    ull m = tog;
    while (m) {
        int pc = rfl(__popcll(m));
        if (pc > 4)      gstep2<8>(tabA, tabB, m, cur, rowbase, cx, accA, accB);
        else if (pc > 2) gstep2<4>(tabA, tabB, m, cur, rowbase, cx, accA, accB);
        else             gstep2<2>(tabA, tabB, m, cur, rowbase, cx, accA, accB);
    }
#pragma unroll
    for (int c = 0; c < 4; ++c) {
        atomicAdd((ull*)&dstA[c * DSTR + lane], (ull)accA[c]);
        atomicAdd((ull*)&dstB[c * DSTR + lane], (ull)accB[c]);
    }
}

#define INV30 9.31322574615478515625e-10   // 2^-30, exact

// 9-wave (576-thread) SINGLE-barrier pipeline (r18 champion + one edit).
// Round-21 edit (L1 waves only): wx(i+1) reads vectorized IN PLACE — 5 x
// ds_read_b128 at the same post-gather position where the champion's 20
// scalar reads provably don't spill (liveness stays local to the tail; the
// r17/r19 spill mode was moving them ACROSS the gather). FMA order f=0..19
// preserved via .x/.y/.z/.w -> bit-identical wx.
__global__ __launch_bounds__(576, 1) void snn_main(
    const float* __restrict__ x,
    const float* __restrict__ W1, const float* __restrict__ b1,
    const float* __restrict__ beta1,
    const float* __restrict__ b2, const float* __restrict__ beta2,
    const int* __restrict__ V1q, const int* __restrict__ V2q,
    const int* __restrict__ W2Tq, const int* __restrict__ WTq,
    const float* __restrict__ alpha_out, const float* __restrict__ beta_out,
    float* __restrict__ out)
{
    __shared__ float xall[TT * FF];                    // full x sequence, 80 KB
    // delta buffers: drive d (0=V1 1=W2 2=V2 3=O) x slot p x [c][lane] (stride DSTR)
    __shared__ __align__(16) long long dAll[4 * 2 * 4 * DSTR];   // ~17 KB

#define DSL(d, p) (dAll + (((d) * 2 + (p)) * 4) * DSTR)

    const int tid  = threadIdx.x;
    const int wid  = tid >> 6;
    const int lane = tid & 63;
    const int b    = blockIdx.x;
    const float* xg = x + (size_t)b * TT * FF;

    // ---- init: delta buffers + coalesced float4 preload of x (80 KB) ----
    for (int idx = tid; idx < 4 * 2 * 4 * DSTR; idx += 576) dAll[idx] = 0;
    for (int idx = tid; idx < (TT * FF) / 4; idx += 576)
        ((float4*)xall)[idx] = ((const float4*)xg)[idx];

    // L1 state (tid 0..255): W1 row in registers, drive total in register
    float syn1 = 0.f, mem1 = 0.f, beta1r = 0.f, b1r = 0.f, wxv = 0.f;
    float w1r[FF];
    long long TV1 = 0;
    bool spk1 = false;
    ull cur1 = 0ull;
    if (tid < HH) {
        beta1r = beta1[tid]; b1r = b1[tid];
#pragma unroll
        for (int f = 0; f < FF; ++f) w1r[f] = W1[tid * FF + f];
    }

    // L2 state (tid 256..511)
    float syn2 = 0.f, mem2 = 0.f, beta2r = 0.f, b2r = 0.f;
    long long TW2 = 0, TV2 = 0;
    bool spk2 = false;
    ull cur2 = 0ull;
    if (wid >= 4 && wid < 8) { beta2r = beta2[tid - HH]; b2r = b2[tid - HH]; }

    // output state (wave 8)
    float synO[4] = {0,0,0,0}, memO[4] = {0,0,0,0}, accO[4] = {0,0,0,0};
    float aOr[4] = {0,0,0,0}, bOr[4] = {0,0,0,0};
    long long TOq[4] = {0, 0, 0, 0};
    bool  spkO[4] = {false,false,false,false};
    float Mrun = 0.f;                    // running softmax shift (wave-uniform)
    if (wid == 8) {
#pragma unroll
        for (int r = 0; r < 4; ++r) {
            int o = lane + (r << 6);
            if (o < OO) { aOr[r] = alpha_out[o]; bOr[r] = beta_out[o]; }
        }
    }
    __syncthreads();
    if (tid < HH) {   // wx for t=0 (from LDS-resident x)
        float wx = b1r;
#pragma unroll
        for (int f = 0; f < FF; ++f) wx = fmaf(xall[f], w1r[f], wx);
        wxv = wx;
    }
    __syncthreads();

    for (int i = 0; i < TT + 2; ++i) {
        const int rp = (i - 1) & 1;   // fold slot (written last interval)
        const int wp = i & 1;         // gather-commit slot
        if (wid < 4) {
            // ---- L1: update(i) + gather + wx(i+1) [vectorized, in place] ----
            if (i < TT) {
                __builtin_amdgcn_s_setprio(1);
                long long* slot = DSL(0, rp);
                int idx = (tid & 3) * DSTR + (tid >> 2);
                TV1 += slot[idx]; slot[idx] = 0;
                float g1 = (float)((double)TV1 * INV30);
                syn1 = fmaf(0.95f, syn1, wxv + g1);
                mem1 = fmaf(beta1r, mem1, syn1) - (spk1 ? 1.f : 0.f);
                spk1 = mem1 > 1.0f;
                ull bal = __ballot(spk1 ? 1 : 0);
                ull tog = cur1 ^ bal;
                cur1 = bal;
                if (tog) gatherPair(W2Tq, V1q, mku(tog), mku(cur1), wid << 6, lane,
                                    DSL(1, wp), DSL(0, wp));
                __builtin_amdgcn_s_setprio(0);
                if ((i + 1) < TT) {
                    // x rows are 80 B = 5 x 16 B, 16B-aligned -> ds_read_b128 x5
                    const float4* xx = (const float4*)(xall + (size_t)(i + 1) * FF);
                    float4 xa = xx[0];
                    float4 xb = xx[1];
                    float4 xc = xx[2];
                    float4 xd = xx[3];
                    float4 xe = xx[4];
                    float wx = b1r;                       // same order f = 0..19
                    wx = fmaf(xa.x, w1r[ 0], wx); wx = fmaf(xa.y, w1r[ 1], wx);
                    wx = fmaf(xa.z, w1r[ 2], wx); wx = fmaf(xa.w, w1r[ 3], wx);
                    wx = fmaf(xb.x, w1r[ 4], wx); wx = fmaf(xb.y, w1r[ 5], wx);
                    wx = fmaf(xb.z, w1r[ 6], wx); wx = fmaf(xb.w, w1r[ 7], wx);
                    wx = fmaf(xc.x, w1r[ 8], wx); wx = fmaf(xc.y, w1r[ 9], wx);
                    wx = fmaf(xc.z, w1r[10], wx); wx = fmaf(xc.w, w1r[11], wx);
                    wx = fmaf(xd.x, w1r[12], wx); wx = fmaf(xd.y, w1r[13], wx);
                    wx = fmaf(xd.z, w1r[14], wx); wx = fmaf(xd.w, w1r[15], wx);
                    wx = fmaf(xe.x, w1r[16], wx); wx = fmaf(xe.y, w1r[17], wx);
                    wx = fmaf(xe.z, w1r[18], wx); wx = fmaf(xe.w, w1r[19], wx);
                    wxv = wx;
                }
            }
        } else if (wid < 8) {
            // ---- L2: update(i-1) + gather; both fold reads in one window ----
            if (i >= 1 && i <= TT) {
                __builtin_amdgcn_s_setprio(1);
                int j = tid - HH;
                int idx = (j & 3) * DSTR + (j >> 2);
                long long* sA = DSL(1, rp);
                long long* sB = DSL(2, rp);
                long long dA = sA[idx];
                long long dB = sB[idx];
                sA[idx] = 0;
                sB[idx] = 0;
                TW2 += dA;
                TV2 += dB;
                float gA = (float)((double)TW2 * INV30);
                float gB = (float)((double)TV2 * INV30);
                syn2 = fmaf(0.95f, syn2, b2r + gA + gB);
                mem2 = fmaf(beta2r, mem2, syn2) - (spk2 ? 1.f : 0.f);
                spk2 = mem2 > 1.0f;
                ull bal = __ballot(spk2 ? 1 : 0);
                ull tog = cur2 ^ bal;
                cur2 = bal;
                if (tog) gatherPair(WTq, V2q, mku(tog), mku(cur2), (wid - 4) << 6, lane,
                                    DSL(3, wp), DSL(2, wp));
                __builtin_amdgcn_s_setprio(0);
            }
        } else {
            // ---- wave 8: output step F(i-2) only (no global loads in loop) ----
            if (i >= 2) {
                int tF = i - 2;
                long long* sO = DSL(3, rp);
                // batch-issue the 4 fold reads (named scalars), zero, then consume
                const int x0 = ((lane      ) & 3) * DSTR + ((lane      ) >> 2);
                const int x1 = ((lane +  64) & 3) * DSTR + ((lane +  64) >> 2);
                const int x2 = ((lane + 128) & 3) * DSTR + ((lane + 128) >> 2);
                const int x3 = ((lane + 192) & 3) * DSTR + ((lane + 192) >> 2);
                long long q0 = sO[x0];
                long long q1 = sO[x1];
                long long q2 = sO[x2];
                long long q3 = sO[x3];
                sO[x0] = 0; sO[x1] = 0; sO[x2] = 0; sO[x3] = 0;
                TOq[0] += q0; TOq[1] += q1; TOq[2] += q2; TOq[3] += q3;
#pragma unroll
                for (int r = 0; r < 4; ++r) {
                    int o = lane + (r << 6);
                    if (o < OO) {
                        float ot = (float)((double)TOq[r] * INV30);
                        synO[r] = fmaf(aOr[r], synO[r], ot);
                        memO[r] = fmaf(bOr[r], memO[r], synO[r]) - (spkO[r] ? 1.f : 0.f);
                        spkO[r] = memO[r] > 1.0f;
                    }
                }
                // running-shift softmax: ex/se use Mrun (prev step's max);
                // the new-max butterfly runs INTERLEAVED with the sum butterfly.
                float ex[4]; float se = 0.f; float nmax = -3.402823466e38f;
#pragma unroll
                for (int r = 0; r < 4; ++r) {
                    int o = lane + (r << 6);
                    if (o < OO) {
                        ex[r] = __expf(memO[r] - Mrun);
                        se += ex[r];
                        nmax = fmaxf(nmax, memO[r]);
                    } else {
                        ex[r] = 0.f;
                    }
                }
#pragma unroll
                for (int off = 32; off; off >>= 1) {
                    se   += __shfl_xor(se, off, 64);
                    nmax  = fmaxf(nmax, __shfl_xor(nmax, off, 64));
                }
                if (tF > 10) {
                    float inv = __builtin_amdgcn_rcpf(se);
#pragma unroll
                    for (int r = 0; r < 4; ++r) accO[r] += ex[r] * inv;
                }
                Mrun = nmax;
            }
        }
        __syncthreads();
    }

    if (wid == 8) {
#pragma unroll
        for (int r = 0; r < 4; ++r) {
            int o = lane + (r << 6);
            if (o < OO) out[(size_t)b * OO + o] = accO[r];
        }
    }
}

// one-shot prep: padded 257x256 int32 fixed-point (2^30) tables, zero diagonal
// (V1q/V2q), zero row 256, WTq cols >= 200 zero.
__global__ void prep_kernel(const float* __restrict__ Vrec1, const float* __restrict__ Vrec2,
                            const float* __restrict__ W2, const float* __restrict__ Wout,
                            int* __restrict__ V1q, int* __restrict__ V2q,
                            int* __restrict__ W2Tq, int* __restrict__ WTq) {
    int idx = blockIdx.x * blockDim.x + threadIdx.x;   // 257*256 entries
    if (idx >= 257 * 256) return;
    int r = idx >> 8, c = idx & 255;
    float v1 = 0.f, v2 = 0.f, w2 = 0.f, wo = 0.f;
    if (r < 256) {
        if (r != c) { v1 = Vrec1[r * HH + c]; v2 = Vrec2[r * HH + c]; }
        w2 = W2[c * HH + r];
        if (c < OO) wo = Wout[c * HH + r];
    }
    const float S = 1073741824.0f;   // 2^30
    V1q[idx]  = __float2int_rn(v1 * S);
    V2q[idx]  = __float2int_rn(v2 * S);
    W2Tq[idx] = __float2int_rn(w2 * S);
    WTq[idx]  = __float2int_rn(wo * S);
}

extern "C" void kernel_launch(void* const* d_in, const int* in_sizes, int n_in,
                              void* d_out, int out_size, void* d_ws, size_t ws_size,
                              hipStream_t stream) {
    const float* x       = (const float*)d_in[0];
    const float* W1      = (const float*)d_in[1];
    const float* b1      = (const float*)d_in[2];
    const float* Vrec1   = (const float*)d_in[3];
    const float* beta1   = (const float*)d_in[4];
    const float* W2      = (const float*)d_in[5];
    const float* b2      = (const float*)d_in[6];
    const float* Vrec2   = (const float*)d_in[7];
    const float* beta2   = (const float*)d_in[8];
    const float* Wout    = (const float*)d_in[9];
    const float* alpha_o = (const float*)d_in[10];
    const float* beta_o  = (const float*)d_in[11];

    const int TBL = 257 * 256;       // int32 per padded table
    int* V1q  = (int*)d_ws;
    int* V2q  = V1q + TBL;
    int* W2Tq = V2q + TBL;
    int* WTq  = W2Tq + TBL;          // total ~1.05 MB of ws

    prep_kernel<<<(TBL + 255) / 256, 256, 0, stream>>>(Vrec1, Vrec2, W2, Wout,
                                                       V1q, V2q, W2Tq, WTq);
    snn_main<<<128, 576, 0, stream>>>(x, W1, b1, beta1, b2, beta2,
                                      V1q, V2q, W2Tq, WTq,
                                      alpha_o, beta_o, (float*)d_out);
}